// Round 14
// baseline (378.787 us; speedup 1.0000x reference)
//
#include <hip/hip_runtime.h>
#include <math.h>

// Problem constants (from setup_inputs; k==8 is fixed by the harness inputs).
constexpr int B_   = 4;
constexpr int P_   = 384;
constexpr int M_   = 64;
constexpr int TOK  = 1024;
constexpr int C    = 128;
constexpr int RC   = 12;
constexpr int RP   = 12;
constexpr int KNN  = 8;
constexpr int GS   = 12;           // group size (both ctx clusters and pred rings)
constexpr int NCTX = P_ * RC;      // 4608 ctx points per batch
constexpr int NPRD = M_ * RP;      // 768 pred points per batch
constexpr int NALL = NCTX + NPRD;  // 5376
constexpr int NG1  = NCTX / GS;    // 384 groups, stage 1
constexpr int NG3  = NALL / GS;    // 448 groups, stage 3
constexpr int TROWS = B_ * P_ + B_ * M_;  // 1792 token rows (ctx then pred)
constexpr int KSPLIT = 4;          // t12 split-K factor

// fused-grid split points
constexpr int ABALL_BLOCKS = (B_ * NALL) / 8;      // 2688 (stage-1/2 AB, global rows)
constexpr int KNN1_BLOCKS  = B_ * (NG1 / 4);       // 384
constexpr int KNS_BLOCKS   = (B_ * M_ * RP) / 256; // 12
constexpr int P3G_BLOCKS   = (B_ * NALL) / 64;     // 336 (stage-3 MFMA GEMM)
constexpr int KNN3C_BLOCKS = B_ * (NG1 / 4);       // 384 (ctx groups, wave-per-group)
constexpr int KNN3P_BLOCKS = (B_ * NPRD) / 4;      // 768 (pred queries, wave-per-query)

typedef __attribute__((ext_vector_type(8))) short bf16x8;
typedef __attribute__((ext_vector_type(4))) float f32x4;

__device__ inline unsigned short f32_to_bf16_rne(float x) {
  union { float f; unsigned int u; } v; v.f = x;
  unsigned int r = v.u + 0x7fffu + ((v.u >> 16) & 1u);
  return (unsigned short)(r >> 16);
}
__device__ inline float bf16_to_f32(unsigned short h) {
  union { float f; unsigned int u; } v; v.u = ((unsigned int)h) << 16;
  return v.f;
}
// convert 8 fp32 (two f32x4) to bf16 hi/lo fragments in registers
__device__ inline void split8(const f32x4& a0, const f32x4& a1, bf16x8& hi, bf16x8& lo) {
  float vals[8] = {a0.x, a0.y, a0.z, a0.w, a1.x, a1.y, a1.z, a1.w};
  union { unsigned short s[8]; bf16x8 v; } oh, ol;
  #pragma unroll
  for (int e = 0; e < 8; ++e) {
    unsigned short h = f32_to_bf16_rne(vals[e]);
    oh.s[e] = h;
    ol.s[e] = f32_to_bf16_rne(vals[e] - bf16_to_f32(h));
  }
  hi = oh.v; lo = ol.v;
}

// ---------------------------------------------------------------------------
// FUSED prep1: Wcat | We2 transpose | anchor | W1T transposes (Wc1/Wq1/Wf1).
__global__ __launch_bounds__(256) void prep1_kernel(const float* __restrict__ We1,
                                                    const float* __restrict__ We2,
                                                    const float* __restrict__ cxyz,
                                                    const float* __restrict__ Wc1,
                                                    const float* __restrict__ Wq1,
                                                    const float* __restrict__ Wf1,
                                                    float* __restrict__ Wcat,
                                                    unsigned short* __restrict__ we2hi,
                                                    unsigned short* __restrict__ we2lo,
                                                    float* __restrict__ anchor,
                                                    unsigned short* __restrict__ w1T_hi,
                                                    unsigned short* __restrict__ w1T_lo) {
  const int tid = threadIdx.x;
  if (blockIdx.x < 131) {
    int n = blockIdx.x * 256 + tid;
    int t = n >> 8, cc = n & 255;
    float v;
    if (cc < C) v = We1[t * C + cc] - We1[(131 + t) * C + cc];
    else        v = We1[(131 + t) * C + (cc - C)];
    Wcat[n] = v;
  } else if (blockIdx.x < 195) {
    int e = (blockIdx.x - 131) * 256 + tid;
    int n = e >> 7, k = e & 127;
    float w = We2[k * C + n];
    unsigned short h = f32_to_bf16_rne(w);
    we2hi[n * C + k] = h;
    we2lo[n * C + k] = f32_to_bf16_rne(w - bf16_to_f32(h));
  } else if (blockIdx.x == 195) {
    const int w = tid >> 6, lane = tid & 63;
    float ax = 0.f, ay = 0.f, az = 0.f;
    for (int p = lane; p < P_; p += 64) {
      const float* c = &cxyz[(w * P_ + p) * 3];
      ax += c[0]; ay += c[1]; az += c[2];
    }
    for (int o = 32; o > 0; o >>= 1) {
      ax += __shfl_down(ax, o);
      ay += __shfl_down(ay, o);
      az += __shfl_down(az, o);
    }
    if (lane == 0) {
      anchor[w * 3 + 0] = ax * (1.0f / (float)P_);
      anchor[w * 3 + 1] = ay * (1.0f / (float)P_);
      anchor[w * 3 + 2] = az * (1.0f / (float)P_);
    }
  } else {
    int e = (blockIdx.x - 196) * 256 + tid;     // 0 .. 3*16384-1
    int wsel = e >> 14, r = e & 16383;
    int c = r >> 7, k = r & 127;
    const float* W1s = (wsel == 0) ? Wc1 : (wsel == 1) ? Wq1 : Wf1;
    float w = W1s[k * C + c];
    unsigned short h = f32_to_bf16_rne(w);
    w1T_hi[(size_t)wsel * 16384 + c * 128 + k] = h;
    w1T_lo[(size_t)wsel * 16384 + c * 128 + k] = f32_to_bf16_rne(w - bf16_to_f32(h));
  }
}

// ---------------------------------------------------------------------------
// FUSED prep2: WbigT hi/lo | cb vector | WcatT hi/lo (feat part, [256][128]).
__global__ __launch_bounds__(256) void prep2_kernel(const float* __restrict__ Wp,
                                                    const float* __restrict__ bp,
                                                    const float* __restrict__ Wcat,
                                                    const float* __restrict__ be1,
                                                    unsigned short* __restrict__ wbT_hi,
                                                    unsigned short* __restrict__ wbT_lo,
                                                    float* __restrict__ cb,
                                                    unsigned short* __restrict__ wcatT_hi,
                                                    unsigned short* __restrict__ wcatT_lo) {
  __shared__ float s_lds[4][128];
  const int tid = threadIdx.x;
  if (blockIdx.x < TOK / 4) {
    const int k0 = blockIdx.x * 4;
    for (int l = tid; l < 4 * 128; l += 256) {
      int r = l >> 7, f = l & 127;
      s_lds[r][f] = Wp[(k0 + r) * C + f];
    }
    __syncthreads();
    float acc[4] = {0.f, 0.f, 0.f, 0.f};
    #pragma unroll 4
    for (int f = 0; f < 128; ++f) {
      float wv = Wcat[f * 256 + tid];
      #pragma unroll
      for (int r = 0; r < 4; ++r) acc[r] = fmaf(s_lds[r][f], wv, acc[r]);
    }
    #pragma unroll
    for (int r = 0; r < 4; ++r) {
      unsigned short h = f32_to_bf16_rne(acc[r]);
      wbT_hi[(size_t)tid * TOK + k0 + r] = h;
      wbT_lo[(size_t)tid * TOK + k0 + r] = f32_to_bf16_rne(acc[r] - bf16_to_f32(h));
    }
  } else if (blockIdx.x == TOK / 4) {
    if (tid < 128) s_lds[0][tid] = bp[tid];
    __syncthreads();
    float a = (tid < 128) ? be1[tid] : 0.f;
    #pragma unroll 4
    for (int f = 0; f < 128; ++f) a = fmaf(s_lds[0][f], Wcat[f * 256 + tid], a);
    cb[tid] = a;
  } else {
    int e = (blockIdx.x - TOK / 4 - 1) * 256 + tid;   // 0 .. 256*128-1
    int c = e >> 7, k = e & 127;
    float w = Wcat[k * 256 + c];
    unsigned short h = f32_to_bf16_rne(w);
    wcatT_hi[c * 128 + k] = h;
    wcatT_lo[c * 128 + k] = f32_to_bf16_rne(w - bf16_to_f32(h));
  }
}

// ---------------------------------------------------------------------------
// FUSED geometry build: ctx points (+radmax zero-init) | pred points.
__global__ __launch_bounds__(256) void build_all_kernel(const float* __restrict__ cxyz,
                                                        const float* __restrict__ noise_c,
                                                        const float* __restrict__ noise_p,
                                                        const float* __restrict__ anchor,
                                                        float* __restrict__ xyz_all,
                                                        int* __restrict__ radmax) {
  if (blockIdx.x < 72) {
    int n = blockIdx.x * 256 + threadIdx.x;
    if (n < B_ * NG3) radmax[n] = 0;      // float 0.0 bits
    int b = n / NCTX, i = n % NCTX, p = i / RC;
    float x = noise_c[n * 3 + 0], y = noise_c[n * 3 + 1], z = noise_c[n * 3 + 2];
    float s = 0.02f / (sqrtf(x * x + y * y + z * z) + 1e-6f);
    const float* c = &cxyz[(b * P_ + p) * 3];
    float* o = &xyz_all[(b * NALL + i) * 3];
    o[0] = c[0] + x * s;
    o[1] = c[1] + y * s;
    o[2] = c[2] + z * s;
  } else {
    int n = (blockIdx.x - 72) * 256 + threadIdx.x;
    int b = n / NPRD, i = n % NPRD;
    float x = noise_p[n * 3 + 0], y = noise_p[n * 3 + 1], z = noise_p[n * 3 + 2];
    float s = 0.05f / (sqrtf(x * x + y * y + z * z) + 1e-6f);
    const float* a = &anchor[b * 3];
    float* o = &xyz_all[(b * NALL + NCTX + i) * 3];
    o[0] = a[0] + x * s;
    o[1] = a[1] + y * s;
    o[2] = a[2] + z * s;
  }
}

// ---------------------------------------------------------------------------
// Tpart[s][row][c] = tok[row] @ Wbig[kslice s]. Split-bf16 MFMA GEMM, split-K.
__global__ __launch_bounds__(256) void t12_mfma_kernel(const float* __restrict__ ctx_tok,
                                                       const float* __restrict__ pred_tok,
                                                       const unsigned short* __restrict__ wbT_hi,
                                                       const unsigned short* __restrict__ wbT_lo,
                                                       float* __restrict__ Tpart) {
  __shared__ unsigned short ahi[64 * 128];   // 16 KB
  __shared__ unsigned short alo[64 * 128];   // 16 KB
  __shared__ unsigned short bhi[128 * 128];  // 32 KB
  const int tid = threadIdx.x;
  const int r0 = blockIdx.x * 64;
  const int n0 = blockIdx.y * 128;
  const int s  = blockIdx.z;
  const float* src = (r0 < B_ * P_) ? (ctx_tok + (size_t)r0 * TOK)
                                    : (pred_tok + (size_t)(r0 - B_ * P_) * TOK);
  const int lane = tid & 63, w = tid >> 6;
  const int m = lane & 15, quad = lane >> 4;

  f32x4 acc[8];
  #pragma unroll
  for (int nt = 0; nt < 8; ++nt) acc[nt] = (f32x4){0.f, 0.f, 0.f, 0.f};

  #pragma unroll 1
  for (int kc = s * (8 / KSPLIT); kc < (s + 1) * (8 / KSPLIT); ++kc) {
    __syncthreads();
    #pragma unroll
    for (int i = 0; i < 4; ++i) {
      int task = tid + 256 * i;           // 0..1023
      int r = task >> 4, c = task & 15;
      const float* sp = src + (size_t)r * TOK + kc * 128 + c * 8;
      f32x4 a0 = *(const f32x4*)sp;
      f32x4 a1 = *(const f32x4*)(sp + 4);
      bf16x8 oh, ol;
      split8(a0, a1, oh, ol);
      int dst = (r * 16 + (c ^ (r & 15))) * 8;
      *(bf16x8*)(ahi + dst) = oh;
      *(bf16x8*)(alo + dst) = ol;
    }
    #pragma unroll
    for (int i = 0; i < 8; ++i) {
      int task = tid + 256 * i;           // 0..2047
      int n = task >> 4, c = task & 15;
      f32x4 v = *(const f32x4*)(wbT_hi + (size_t)(n0 + n) * TOK + kc * 128 + c * 8);
      *(f32x4*)(bhi + (n * 16 + (c ^ (n & 15))) * 8) = v;
    }
    __syncthreads();
    #pragma unroll
    for (int ks = 0; ks < 4; ++ks) {
      int c0 = ks * 4 + quad;
      int aoff = ((w * 16 + m) * 16 + (c0 ^ m)) * 8;
      bf16x8 av  = *(const bf16x8*)(ahi + aoff);
      bf16x8 av2 = *(const bf16x8*)(alo + aoff);
      #pragma unroll
      for (int nt = 0; nt < 8; ++nt) {
        int n = nt * 16 + m;
        bf16x8 bh = *(const bf16x8*)(bhi + (n * 16 + (c0 ^ m)) * 8);
        bf16x8 bl = *(const bf16x8*)(wbT_lo + (size_t)(n0 + n) * TOK + kc * 128 + c0 * 8);
        acc[nt] = __builtin_amdgcn_mfma_f32_16x16x32_bf16(av, bh, acc[nt], 0, 0, 0);
        acc[nt] = __builtin_amdgcn_mfma_f32_16x16x32_bf16(av, bl, acc[nt], 0, 0, 0);
        acc[nt] = __builtin_amdgcn_mfma_f32_16x16x32_bf16(av2, bh, acc[nt], 0, 0, 0);
      }
    }
  }
  #pragma unroll
  for (int nt = 0; nt < 8; ++nt) {
    int col = n0 + nt * 16 + m;
    #pragma unroll
    for (int reg = 0; reg < 4; ++reg) {
      int row = r0 + w * 16 + quad * 4 + reg;
      Tpart[((size_t)s * TROWS + row) * 256 + col] = acc[nt][reg];
    }
  }
}

// ---------------------------------------------------------------------------
// Wave-per-group kNN body for CTX groups. Outputs GLOBAL point rows.
template <int STAGE>
__device__ __forceinline__ void knn_wave_body(
    const float* __restrict__ xyz_all, const float* __restrict__ ctx_xyz,
    const float* __restrict__ anchor, const int* __restrict__ radmax,
    int b, int p, int lane,
    float4* own, int* gl, float4* tile, int* tilei,
    int* __restrict__ idx_out) {
  const int NG  = (STAGE == 1) ? NG1 : NG3;
  const float* base = xyz_all + (size_t)b * NALL * 3;
  const float* cxb  = ctx_xyz + (size_t)b * P_ * 3;
  const bool owner = lane < GS;
  const int qloc = p * GS + lane;

  auto sph = [&](int g) -> float4 {
    float4 c;
    float rad;
    if (STAGE == 1) {
      c = make_float4(cxb[g * 3 + 0], cxb[g * 3 + 1], cxb[g * 3 + 2], 0.f);
      rad = 0.0201f;
    } else {
      float moff = __int_as_float(radmax[b * NG3 + g]);
      if (g < NG1) {
        c = make_float4(cxb[g * 3 + 0], cxb[g * 3 + 1], cxb[g * 3 + 2], 0.f);
        rad = 0.0201f + moff * 1.0002f + 1e-6f;
      } else {
        c = make_float4(anchor[b * 3 + 0], anchor[b * 3 + 1], anchor[b * 3 + 2], 0.f);
        rad = 0.0501f + moff * 1.0002f + 1e-6f;
      }
    }
    c.w = rad;
    return c;
  };

  if (owner) {
    float x = base[qloc * 3 + 0], y = base[qloc * 3 + 1], z = base[qloc * 3 + 2];
    own[lane] = make_float4(x, y, z, x * x + y * y + z * z);
  }
  float qx = 0.f, qy = 0.f, qz = 0.f, sqi = 0.f;
  if (owner) {
    float4 q = own[lane];
    qx = q.x; qy = q.y; qz = q.z; sqi = q.w;
  }

  float bd[KNN];
  int   bi[KNN];
  #pragma unroll
  for (int u = 0; u < KNN; ++u) { bd[u] = 3e38f; bi[u] = 0x7fffffff; }

  #pragma unroll 1
  for (int j = 0; j < GS; ++j) {
    float4 cj = own[j];
    float d2 = sqi + cj.w - 2.0f * (qx * cj.x + qy * cj.y + qz * cj.z);
    if (owner && j != lane && d2 < bd[KNN - 1]) {
      bd[KNN - 1] = d2; bi[KNN - 1] = p * GS + j;
      #pragma unroll
      for (int u = KNN - 1; u > 0; --u) {
        if (bd[u] < bd[u - 1]) {
          float td = bd[u]; bd[u] = bd[u - 1]; bd[u - 1] = td;
          int   ti = bi[u]; bi[u] = bi[u - 1]; bi[u - 1] = ti;
        }
      }
    }
  }

  float t = owner ? bd[KNN - 1] : 0.f;
  #pragma unroll
  for (int mm = 1; mm < 64; mm <<= 1) t = fmaxf(t, __shfl_xor(t, mm));
  float r = sqrtf(fmaxf(t, 0.f)) * 1.001f + 1e-6f;

  const float4 gp = sph(p);
  const float rlim = r + gp.w;

  int ng = 0;
  #pragma unroll 1
  for (int gs0 = 0; gs0 < NG; gs0 += 64) {
    int g = gs0 + lane;
    bool ok = false;
    if (g < NG && g != p) {
      float4 gq = sph(g);
      float dx = gq.x - gp.x, dy = gq.y - gp.y, dz = gq.z - gp.z;
      float lim = rlim + gq.w;
      ok = (dx * dx + dy * dy + dz * dz) < lim * lim * 1.001f;
    }
    unsigned long long mask = __ballot(ok);
    if (ok) gl[ng + (int)__popcll(mask & ((1ull << lane) - 1ull))] = g;
    ng += (int)__popcll(mask);
  }

  const int total = ng * GS;
  #pragma unroll 1
  for (int cs = 0; cs < total; cs += 64) {
    int ci = cs + lane;
    if (ci < total) {
      int gg = gl[ci / GS];
      int j  = ci % GS;
      int jloc = gg * GS + j;
      float x = base[jloc * 3 + 0], y = base[jloc * 3 + 1], z = base[jloc * 3 + 2];
      tile[lane] = make_float4(x, y, z, x * x + y * y + z * z);
      tilei[lane] = jloc;
    }
    int nj = min(64, total - cs);
    #pragma unroll 1
    for (int jj = 0; jj < nj; ++jj) {
      float4 tt = tile[jj];
      int ti0 = tilei[jj];
      float d2 = sqi + tt.w - 2.0f * (qx * tt.x + qy * tt.y + qz * tt.z);
      if (owner && d2 < bd[KNN - 1]) {
        bd[KNN - 1] = d2; bi[KNN - 1] = ti0;
        #pragma unroll
        for (int u = KNN - 1; u > 0; --u) {
          if (bd[u] < bd[u - 1]) {
            float td = bd[u]; bd[u] = bd[u - 1]; bd[u - 1] = td;
            int   ti = bi[u]; bi[u] = bi[u - 1]; bi[u - 1] = ti;
          }
        }
      }
    }
  }

  if (owner) {
    int gid = b * NALL + qloc;            // GLOBAL point row
    #pragma unroll
    for (int u = 0; u < KNN; ++u) idx_out[gid * KNN + u] = b * NALL + bi[u];
  }
}

// ---------------------------------------------------------------------------
// Wave-per-QUERY kNN for stage-3 PRED points (lane-partitioned scan + merge).
__device__ __forceinline__ void knn3_pred_wave(
    const float* __restrict__ xyz_all, const float* __restrict__ ctx_xyz,
    const float* __restrict__ anchor, const int* __restrict__ radmax,
    int b, int q, int lane, int* gl, int* __restrict__ idx_out) {
  const float* base = xyz_all + (size_t)b * NALL * 3;
  const float* cxb  = ctx_xyz + (size_t)b * P_ * 3;
  const int qloc = NCTX + q;
  const int p = NG1 + q / GS;

  const float qx = base[qloc * 3 + 0], qy = base[qloc * 3 + 1], qz = base[qloc * 3 + 2];
  const float sqi = qx * qx + qy * qy + qz * qz;

  float dcur = 3e38f;
  int   icur = 0x7fffffff;
  if (lane < GS) {
    int jloc = p * GS + lane;
    if (jloc != qloc) {
      float x = base[jloc * 3 + 0], y = base[jloc * 3 + 1], z = base[jloc * 3 + 2];
      dcur = sqi + (x * x + y * y + z * z) - 2.0f * (qx * x + qy * y + qz * z);
      icur = jloc;
    }
  }
  float t = 3e38f;
  #pragma unroll 1
  for (int r8 = 0; r8 < KNN; ++r8) {
    float d = dcur; int i = icur;
    #pragma unroll
    for (int mm = 1; mm < 64; mm <<= 1) {
      float od = __shfl_xor(d, mm);
      int   oi = __shfl_xor(i, mm);
      if (od < d || (od == d && oi < i)) { d = od; i = oi; }
    }
    t = d;
    if (icur == i) { dcur = 3e38f; icur = 0x7fffffff; }
  }
  float r = sqrtf(fmaxf(t, 0.f)) * 1.001f + 1e-6f;

  int ng = 0;
  #pragma unroll 1
  for (int gs0 = 0; gs0 < NG3; gs0 += 64) {
    int g = gs0 + lane;
    bool ok = false;
    if (g < NG3) {
      float cx, cy, cz, rad;
      float moff = __int_as_float(radmax[b * NG3 + g]) * 1.0002f + 1e-6f;
      if (g < NG1) {
        cx = cxb[g * 3 + 0]; cy = cxb[g * 3 + 1]; cz = cxb[g * 3 + 2];
        rad = 0.0201f + moff;
      } else {
        cx = anchor[b * 3 + 0]; cy = anchor[b * 3 + 1]; cz = anchor[b * 3 + 2];
        rad = 0.0501f + moff;
      }
      float dx = cx - qx, dy = cy - qy, dz = cz - qz;
      float lim = r + rad;
      ok = (dx * dx + dy * dy + dz * dz) < lim * lim * 1.001f;
    }
    unsigned long long mask = __ballot(ok);
    if (ok) gl[ng + (int)__popcll(mask & ((1ull << lane) - 1ull))] = g;
    ng += (int)__popcll(mask);
  }

  float bd[KNN];
  int   bi[KNN];
  #pragma unroll
  for (int u = 0; u < KNN; ++u) { bd[u] = 3e38f; bi[u] = 0x7fffffff; }
  const int total = ng * GS;
  #pragma unroll 2
  for (int ci = lane; ci < total; ci += 64) {
    int gg = gl[ci / GS];
    int j  = ci % GS;
    int jloc = gg * GS + j;
    float x = base[jloc * 3 + 0], y = base[jloc * 3 + 1], z = base[jloc * 3 + 2];
    float d2 = sqi + (x * x + y * y + z * z) - 2.0f * (qx * x + qy * y + qz * z);
    if (jloc != qloc && d2 < bd[KNN - 1]) {
      bd[KNN - 1] = d2; bi[KNN - 1] = jloc;
      #pragma unroll
      for (int u = KNN - 1; u > 0; --u) {
        if (bd[u] < bd[u - 1]) {
          float td = bd[u]; bd[u] = bd[u - 1]; bd[u - 1] = td;
          int   ti = bi[u]; bi[u] = bi[u - 1]; bi[u - 1] = ti;
        }
      }
    }
  }

  const int gid = b * NALL + qloc;
  #pragma unroll 1
  for (int r8 = 0; r8 < KNN; ++r8) {
    float d = bd[0]; int i = bi[0];
    #pragma unroll
    for (int mm = 1; mm < 64; mm <<= 1) {
      float od = __shfl_xor(d, mm);
      int   oi = __shfl_xor(i, mm);
      if (od < d || (od == d && oi < i)) { d = od; i = oi; }
    }
    if (lane == 0) idx_out[gid * KNN + r8] = b * NALL + i;
    if (bi[0] == i) {
      #pragma unroll
      for (int u = 0; u < KNN - 1; ++u) { bd[u] = bd[u + 1]; bi[u] = bi[u + 1]; }
      bd[KNN - 1] = 3e38f; bi[KNN - 1] = 0x7fffffff;
    }
  }
}

// ---------------------------------------------------------------------------
// FUSED stage-1/2: AB assembly for ALL points (global-row layout) + stage-1
// ctx-group kNN + stage-2 small kNN. idxA holds GLOBAL point rows.
__global__ __launch_bounds__(256) void ab12_knn12_kernel(
    const float* __restrict__ Tp, const float* __restrict__ xyz_all,
    const float* __restrict__ Wcat, const float* __restrict__ cb,
    const float* __restrict__ ctx_xyz,
    float* __restrict__ AB, int* __restrict__ idxA) {
  __shared__ float4 own[4][GS];
  __shared__ int    gl[4][NG1];
  __shared__ float4 tile[4][64];
  __shared__ int    tilei[4][64];
  const int tid = threadIdx.x;
  if (blockIdx.x < ABALL_BLOCKS) {
    const int base = blockIdx.x * 8;
    const float wx = Wcat[128 * 256 + tid];
    const float wy = Wcat[129 * 256 + tid];
    const float wz = Wcat[130 * 256 + tid];
    const float cbv = cb[tid];
    #pragma unroll
    for (int p = 0; p < 8; ++p) {
      int n = base + p;                  // global point row
      int b = n / NALL, row = n % NALL;
      int trow = (row < NCTX) ? (b * (NCTX / GS) + row / GS)
                              : (B_ * P_ + b * (NPRD / GS) + (row - NCTX) / GS);
      const float* xr = xyz_all + (size_t)n * 3;
      float x = xr[0], y = xr[1], z = xr[2];
      float v = cbv;
      #pragma unroll
      for (int s = 0; s < KSPLIT; ++s)
        v += Tp[((size_t)s * TROWS + trow) * 256 + tid];
      v = fmaf(x, wx, v);
      v = fmaf(y, wy, v);
      v = fmaf(z, wz, v);
      AB[(size_t)n * 256 + tid] = v;
    }
  } else if (blockIdx.x < ABALL_BLOCKS + KNN1_BLOCKS) {
    int kblk = blockIdx.x - ABALL_BLOCKS;
    int w = tid >> 6, lane = tid & 63;
    int b = kblk / (NG1 / 4);
    int p = (kblk % (NG1 / 4)) * 4 + w;
    knn_wave_body<1>(xyz_all, ctx_xyz, nullptr, nullptr, b, p, lane,
                     own[w], gl[w], tile[w], tilei[w], idxA);
  } else {
    int q = (blockIdx.x - ABALL_BLOCKS - KNN1_BLOCKS) * 256 + tid;  // 0..3071
    int gr = q / RP, qi = q % RP;
    int b = gr / M_, w = gr % M_;
    const float* base = xyz_all + (size_t)(b * NALL + NCTX + w * RP) * 3;
    float cx[RP], cy[RP], cz[RP], cs[RP];
    #pragma unroll
    for (int j = 0; j < RP; ++j) {
      cx[j] = base[j * 3 + 0]; cy[j] = base[j * 3 + 1]; cz[j] = base[j * 3 + 2];
      cs[j] = cx[j] * cx[j] + cy[j] * cy[j] + cz[j] * cz[j];
    }
    float qx = cx[0], qy = cy[0], qz = cz[0], sqi = cs[0];
    #pragma unroll
    for (int j = 0; j < RP; ++j) {
      if (j == qi) { qx = cx[j]; qy = cy[j]; qz = cz[j]; sqi = cs[j]; }
    }
    float bd[KNN];
    int   bi[KNN];
    #pragma unroll
    for (int u = 0; u < KNN; ++u) { bd[u] = 3e38f; bi[u] = 0; }
    #pragma unroll
    for (int j = 0; j < RP; ++j) {
      float d2 = sqi + cs[j] - 2.0f * (qx * cx[j] + qy * cy[j] + qz * cz[j]);
      if (j != qi && d2 < bd[KNN - 1]) {
        bd[KNN - 1] = d2; bi[KNN - 1] = j;
        #pragma unroll
        for (int u = KNN - 1; u > 0; --u) {
          if (bd[u] < bd[u - 1]) {
            float td = bd[u]; bd[u] = bd[u - 1]; bd[u - 1] = td;
            int   ti = bi[u]; bi[u] = bi[u - 1]; bi[u - 1] = ti;
          }
        }
      }
    }
    int gid = b * NALL + NCTX + w * RP + qi;
    #pragma unroll
    for (int u = 0; u < KNN; ++u)
      idxA[gid * KNN + u] = b * NALL + NCTX + w * RP + bi[u];
  }
}

// ---------------------------------------------------------------------------
// FUSED: stage-3 precompute as LDS-free MFMA GEMM | ctx-group kNN | pred kNN.
__global__ __launch_bounds__(256) void pre3_knn3_kernel(
    const float* __restrict__ feat, const float* __restrict__ xyz_all,
    const float* __restrict__ Wcat, const float* __restrict__ be1,
    const unsigned short* __restrict__ wcatT_hi, const unsigned short* __restrict__ wcatT_lo,
    const float* __restrict__ ctx_xyz, const float* __restrict__ anchor,
    const int* __restrict__ radmax,
    float* __restrict__ AB, int* __restrict__ idx3) {
  __shared__ float4 own[4][GS];
  __shared__ int    gl[4][NG3];
  __shared__ float4 tile[4][64];
  __shared__ int    tilei[4][64];
  const int tid = threadIdx.x;
  if (blockIdx.x < P3G_BLOCKS) {
    const int lane = tid & 63, w = tid >> 6;
    const int m = lane & 15, quad = lane >> 4;
    const int r0 = blockIdx.x * 64;
    const float* arow = feat + (size_t)(r0 + w * 16 + m) * C;

    f32x4 acc[16];
    #pragma unroll
    for (int nt = 0; nt < 16; ++nt) acc[nt] = (f32x4){0.f, 0.f, 0.f, 0.f};

    #pragma unroll
    for (int ks = 0; ks < 4; ++ks) {
      int k0 = ks * 32 + quad * 8;
      f32x4 a0 = *(const f32x4*)(arow + k0);
      f32x4 a1 = *(const f32x4*)(arow + k0 + 4);
      bf16x8 ahi, alo;
      split8(a0, a1, ahi, alo);
      #pragma unroll
      for (int nt = 0; nt < 16; ++nt) {
        int n = nt * 16 + m;
        bf16x8 bh = *(const bf16x8*)(wcatT_hi + n * 128 + k0);
        bf16x8 bl = *(const bf16x8*)(wcatT_lo + n * 128 + k0);
        acc[nt] = __builtin_amdgcn_mfma_f32_16x16x32_bf16(ahi, bh, acc[nt], 0, 0, 0);
        acc[nt] = __builtin_amdgcn_mfma_f32_16x16x32_bf16(ahi, bl, acc[nt], 0, 0, 0);
        acc[nt] = __builtin_amdgcn_mfma_f32_16x16x32_bf16(alo, bh, acc[nt], 0, 0, 0);
      }
    }
    float xr[4], yr[4], zr[4];
    #pragma unroll
    for (int reg = 0; reg < 4; ++reg) {
      int row = r0 + w * 16 + quad * 4 + reg;
      xr[reg] = xyz_all[row * 3 + 0];
      yr[reg] = xyz_all[row * 3 + 1];
      zr[reg] = xyz_all[row * 3 + 2];
    }
    #pragma unroll
    for (int nt = 0; nt < 16; ++nt) {
      int col = nt * 16 + m;
      float cbv = (col < C) ? be1[col] : 0.0f;
      float wx = Wcat[128 * 256 + col];
      float wy = Wcat[129 * 256 + col];
      float wz = Wcat[130 * 256 + col];
      #pragma unroll
      for (int reg = 0; reg < 4; ++reg) {
        int row = r0 + w * 16 + quad * 4 + reg;
        float v = acc[nt][reg] + cbv;
        v = fmaf(xr[reg], wx, v);
        v = fmaf(yr[reg], wy, v);
        v = fmaf(zr[reg], wz, v);
        AB[(size_t)row * 256 + col] = v;
      }
    }
  } else if (blockIdx.x < P3G_BLOCKS + KNN3C_BLOCKS) {
    int kblk = blockIdx.x - P3G_BLOCKS;
    int w = tid >> 6, lane = tid & 63;
    int b = kblk / (NG1 / 4);
    int p = (kblk % (NG1 / 4)) * 4 + w;     // ctx groups only: p < NG1
    knn_wave_body<3>(xyz_all, ctx_xyz, anchor, radmax, b, p, lane,
                     own[w], gl[w], tile[w], tilei[w], idx3);
  } else {
    int kblk = blockIdx.x - P3G_BLOCKS - KNN3C_BLOCKS;
    int w = tid >> 6, lane = tid & 63;
    int wid = kblk * 4 + w;                  // 0 .. B*NPRD-1
    int b = wid / NPRD, q = wid % NPRD;
    knn3_pred_wave(xyz_all, ctx_xyz, anchor, radmax, b, q, lane, gl[w], idx3);
  }
}

// ---------------------------------------------------------------------------
// MFMA EdgeConv core, K-split variant: h hi/lo staged in 64-k halves (16 KB)
// + We2-hi in LDS (32 KB) => 48 KB total -> 3 blocks/CU (was 2 at 64 KB).
// Same coalesced gather and We2 path as the proven round-13 kernel; neighbor
// indices cached in registers across the two halves. XCD-contiguous block
// swizzle gives each XCD a contiguous ~2.75 MB AB slice (L2-resident).
__global__ __launch_bounds__(256) void conv_mfma_kernel(const float* __restrict__ AB,
                                                        const int* __restrict__ idx,
                                                        const unsigned short* __restrict__ w2hi_g,
                                                        const unsigned short* __restrict__ w2lo_g,
                                                        const float* __restrict__ be2,
                                                        float* __restrict__ feat_out) {
  __shared__ unsigned short hhi[64 * 64];     // 8 KB
  __shared__ unsigned short hlo[64 * 64];     // 8 KB
  __shared__ unsigned short w2hi[128 * 128];  // 32 KB
  const int tid = threadIdx.x;
  // XCD-contiguous swizzle (grid = 2688, divisible by 8; bijective remap).
  const int nb = gridDim.x;
  const int blk = (blockIdx.x % 8) * (nb / 8) + (blockIdx.x / 8);
  const int base = blk * 8;

  // stage We2-hi once (swizzled 16B chunks)
  #pragma unroll
  for (int i = 0; i < 8; ++i) {
    int q = tid + 256 * i;
    int n = q >> 4, c = q & 15;
    f32x4 v = *(const f32x4*)(w2hi_g + n * 128 + c * 8);
    *(f32x4*)(w2hi + (n * 16 + (c ^ (n & 15))) * 8) = v;
  }

  // cache this thread's two edge-row neighbor indices (same rows both halves)
  int jreg[2];
  #pragma unroll
  for (int i = 0; i < 2; ++i) {
    int r = (tid >> 3) + 32 * i;
    jreg[i] = idx[(base + (r >> 3)) * KNN + (r & 7)];
  }

  const int lane = tid & 63, w = tid >> 6;
  const int m = lane & 15, quad = lane >> 4;
  f32x4 acc[8];
  #pragma unroll
  for (int nt = 0; nt < 8; ++nt) acc[nt] = (f32x4){0.f, 0.f, 0.f, 0.f};

  #pragma unroll 1
  for (int kh = 0; kh < 2; ++kh) {
    __syncthreads();   // protect h buffers (also orders w2hi staging on kh=0)
    // stage h = relu(A_i + B_j) for k in [kh*64, kh*64+64): 512 tasks of 8
    #pragma unroll
    for (int i = 0; i < 2; ++i) {
      int r = (tid >> 3) + 32 * i;
      int c = tid & 7;
      int g = base + (r >> 3);
      int j = jreg[i];
      const float* aP = AB + (size_t)g * 256 + kh * 64 + c * 8;
      const float* bP = AB + (size_t)j * 256 + 128 + kh * 64 + c * 8;
      f32x4 a0 = *(const f32x4*)aP;
      f32x4 a1 = *(const f32x4*)(aP + 4);
      f32x4 b0 = *(const f32x4*)bP;
      f32x4 b1 = *(const f32x4*)(bP + 4);
      f32x4 s0 = {fmaxf(a0.x + b0.x, 0.f), fmaxf(a0.y + b0.y, 0.f),
                  fmaxf(a0.z + b0.z, 0.f), fmaxf(a0.w + b0.w, 0.f)};
      f32x4 s1 = {fmaxf(a1.x + b1.x, 0.f), fmaxf(a1.y + b1.y, 0.f),
                  fmaxf(a1.z + b1.z, 0.f), fmaxf(a1.w + b1.w, 0.f)};
      bf16x8 oh, ol;
      split8(s0, s1, oh, ol);
      int dst = (r * 8 + (c ^ (r & 7))) * 8;
      *(bf16x8*)(hhi + dst) = oh;
      *(bf16x8*)(hlo + dst) = ol;
    }
    __syncthreads();
    #pragma unroll
    for (int ks2 = 0; ks2 < 2; ++ks2) {
      int c0h = ks2 * 4 + quad;              // within-half 8-chunk index 0..7
      int k0 = kh * 64 + c0h * 8;            // global k offset
      int c16 = kh * 8 + c0h;                // 16-chunk index for w2hi LDS
      int rowA = w * 16 + m;
      int aoff = (rowA * 8 + (c0h ^ (m & 7))) * 8;
      bf16x8 ahi = *(const bf16x8*)(hhi + aoff);
      bf16x8 alo = *(const bf16x8*)(hlo + aoff);
      #pragma unroll
      for (int nt = 0; nt < 8; ++nt) {
        int n = nt * 16 + m;
        bf16x8 bhi = *(const bf16x8*)(w2hi + (n * 16 + (c16 ^ m)) * 8);
        bf16x8 blo = *(const bf16x8*)(w2lo_g + n * 128 + k0);
        acc[nt] = __builtin_amdgcn_mfma_f32_16x16x32_bf16(ahi, bhi, acc[nt], 0, 0, 0);
        acc[nt] = __builtin_amdgcn_mfma_f32_16x16x32_bf16(ahi, blo, acc[nt], 0, 0, 0);
        acc[nt] = __builtin_amdgcn_mfma_f32_16x16x32_bf16(alo, bhi, acc[nt], 0, 0, 0);
      }
    }
  }

  int pt = 2 * w + (quad >> 1);
  int g = base + pt;                         // global point row
  float* orow = feat_out + (size_t)g * C;
  bool writer = (quad & 1) == 0;
  #pragma unroll
  for (int nt = 0; nt < 8; ++nt) {
    float v = fmaxf(fmaxf(acc[nt].x, acc[nt].y), fmaxf(acc[nt].z, acc[nt].w));
    v = fmaxf(v, __shfl_xor(v, 16));
    if (writer) {
      int col = nt * 16 + m;
      orow[col] = v + be2[col];
    }
  }
}

// ---------------------------------------------------------------------------
// MFMA offset MLP over global rows with per-block weight-set selection.
__global__ __launch_bounds__(256) void offset_mfma_kernel(
    const float* __restrict__ feat,
    const unsigned short* __restrict__ w1T_hi_c, const unsigned short* __restrict__ w1T_lo_c,
    const float* __restrict__ b1_c, const float* __restrict__ W2_c, const float* __restrict__ b2_c,
    const unsigned short* __restrict__ w1T_hi_p, const unsigned short* __restrict__ w1T_lo_p,
    const float* __restrict__ b1_p, const float* __restrict__ W2_p, const float* __restrict__ b2_p,
    const float* __restrict__ xyz_in, float* __restrict__ xyz_out,
    int* __restrict__ radmax) {
  const int tid = threadIdx.x;
  const int lane = tid & 63, w = tid >> 6;
  const int m = lane & 15, quad = lane >> 4;
  const int r0 = blockIdx.x * 64;            // global point base
  const bool isCtx = (r0 % NALL) < NCTX;

  const unsigned short* w1T_hi = isCtx ? w1T_hi_c : w1T_hi_p;
  const unsigned short* w1T_lo = isCtx ? w1T_lo_c : w1T_lo_p;
  const float* b1 = isCtx ? b1_c : b1_p;
  const float* W2 = isCtx ? W2_c : W2_p;
  const float* b2 = isCtx ? b2_c : b2_p;

  const float* arow = feat + (size_t)(r0 + w * 16 + m) * C;

  f32x4 acc[8];
  #pragma unroll
  for (int nt = 0; nt < 8; ++nt) acc[nt] = (f32x4){0.f, 0.f, 0.f, 0.f};

  #pragma unroll
  for (int ks = 0; ks < 4; ++ks) {
    int k0 = ks * 32 + quad * 8;
    f32x4 a0 = *(const f32x4*)(arow + k0);
    f32x4 a1 = *(const f32x4*)(arow + k0 + 4);
    bf16x8 ahi, alo;
    split8(a0, a1, ahi, alo);
    #pragma unroll
    for (int nt = 0; nt < 8; ++nt) {
      int n = nt * 16 + m;
      bf16x8 bh = *(const bf16x8*)(w1T_hi + n * 128 + k0);
      bf16x8 bl = *(const bf16x8*)(w1T_lo + n * 128 + k0);
      acc[nt] = __builtin_amdgcn_mfma_f32_16x16x32_bf16(ahi, bh, acc[nt], 0, 0, 0);
      acc[nt] = __builtin_amdgcn_mfma_f32_16x16x32_bf16(ahi, bl, acc[nt], 0, 0, 0);
      acc[nt] = __builtin_amdgcn_mfma_f32_16x16x32_bf16(alo, bh, acc[nt], 0, 0, 0);
    }
  }

  float p0[4] = {0.f, 0.f, 0.f, 0.f};
  float p1[4] = {0.f, 0.f, 0.f, 0.f};
  float p2[4] = {0.f, 0.f, 0.f, 0.f};
  #pragma unroll
  for (int nt = 0; nt < 8; ++nt) {
    int col = nt * 16 + m;
    float b1v = b1[col];
    float w20 = W2[col * 3 + 0], w21 = W2[col * 3 + 1], w22 = W2[col * 3 + 2];
    #pragma unroll
    for (int reg = 0; reg < 4; ++reg) {
      float h = fmaxf(acc[nt][reg] + b1v, 0.0f);
      p0[reg] = fmaf(h, w20, p0[reg]);
      p1[reg] = fmaf(h, w21, p1[reg]);
      p2[reg] = fmaf(h, w22, p2[reg]);
    }
  }
  #pragma unroll
  for (int o = 1; o < 16; o <<= 1) {
    #pragma unroll
    for (int reg = 0; reg < 4; ++reg) {
      p0[reg] += __shfl_xor(p0[reg], o);
      p1[reg] += __shfl_xor(p1[reg], o);
      p2[reg] += __shfl_xor(p2[reg], o);
    }
  }
  if (m == 0) {
    float b20 = b2[0], b21 = b2[1], b22 = b2[2];
    #pragma unroll
    for (int reg = 0; reg < 4; ++reg) {
      int nO = r0 + w * 16 + quad * 4 + reg;   // global point row
      int row = nO * 3;
      float o0 = p0[reg] + b20;
      float o1 = p1[reg] + b21;
      float o2 = p2[reg] + b22;
      xyz_out[row + 0] = xyz_in[row + 0] + o0;
      xyz_out[row + 1] = xyz_in[row + 1] + o1;
      xyz_out[row + 2] = xyz_in[row + 2] + o2;
      if (radmax != nullptr) {
        int b = nO / NALL, loc = nO % NALL;
        float mag = sqrtf(o0 * o0 + o1 * o1 + o2 * o2);
        atomicMax(radmax + b * NG3 + loc / GS, __float_as_int(mag));
      }
    }
  }
}

// ---------------------------------------------------------------------------
extern "C" void kernel_launch(void* const* d_in, const int* in_sizes, int n_in,
                              void* d_out, int out_size, void* d_ws, size_t ws_size,
                              hipStream_t stream) {
  (void)in_sizes; (void)n_in; (void)out_size; (void)ws_size;
  const float* ctx_xyz   = (const float*)d_in[0];
  const float* ctx_tok   = (const float*)d_in[1];
  const float* pred_tok  = (const float*)d_in[2];
  const float* noise_ctx = (const float*)d_in[3];
  const float* noise_prd = (const float*)d_in[4];
  const float* Wp  = (const float*)d_in[5];
  const float* bp  = (const float*)d_in[6];
  const float* We1 = (const float*)d_in[7];
  const float* be1 = (const float*)d_in[8];
  const float* We2 = (const float*)d_in[9];
  const float* be2 = (const float*)d_in[10];
  const float* Wc1 = (const float*)d_in[11];
  const float* bc1 = (const float*)d_in[12];
  const float* Wc2 = (const float*)d_in[13];
  const float* bc2 = (const float*)d_in[14];
  const float* Wq1 = (const float*)d_in[15];
  const float* bq1 = (const float*)d_in[16];
  const float* Wq2 = (const float*)d_in[17];
  const float* bq2 = (const float*)d_in[18];
  const float* Wf1 = (const float*)d_in[19];
  const float* bf1 = (const float*)d_in[20];
  const float* Wf2 = (const float*)d_in[21];
  const float* bf2 = (const float*)d_in[22];
  float* out = (float*)d_out;

  // workspace layout (floats)
  float* ws        = (float*)d_ws;
  float* T         = ws;                          // 1792*256 (legacy slot)
  float* anchor    = T + TROWS * 256;             // 16
  float* xyz_all   = anchor + 16;                 // B*NALL*3    = 64512
  float* feat_in   = xyz_all + B_ * NALL * 3;     // B*NALL*C    = 2752512
  float* feat_out  = feat_in + B_ * NALL * C;     // B*NALL*C    = 2752512
  float* AB        = feat_out + B_ * NALL * C;    // B*NALL*256  = 5505024
  float* Wcat      = AB + B_ * NALL * 256;        // 131*256     = 33536
  float* cb        = Wcat + 131 * 256;            // 256
  int*   idxA      = (int*)(cb + 256);            // B*NALL*8    = 172032 (stages 1/2)
  int*   idx3      = idxA + B_ * NALL * KNN;      // B*NALL*8    = 172032
  unsigned short* we2hi = (unsigned short*)(idx3 + B_ * NALL * KNN); // 16384
  unsigned short* we2lo = we2hi + C * C;                             // 16384
  int*   radmax    = (int*)(we2lo + C * C);       // B*NG3       = 1792 ints
  unsigned short* wcatT_hi = (unsigned short*)(radmax + B_ * NG3);   // 32768
  unsigned short* wcatT_lo = wcatT_hi + 256 * 128;                   // 32768
  unsigned short* w1T_hi   = wcatT_lo + 256 * 128;                   // 3*16384
  unsigned short* w1T_lo   = w1T_hi + 3 * C * C;                     // 3*16384
  // wbT aliases AB: fully consumed by t12_mfma before the first AB write.
  unsigned short* wbT_hi = (unsigned short*)AB;   // 256*1024 ushorts
  unsigned short* wbT_lo = wbT_hi + 256 * TOK;    // 256*1024 ushorts
  // Tpart aliases feat_out: last read at ab12_knn12; feat_out first written at
  // the stage-1/2 conv (after). KSPLIT*TROWS*256 = 1835008 <= 2752512 floats.
  float* Tpart = feat_out;

  // prep (fused)
  prep1_kernel<<<388, 256, 0, stream>>>(We1, We2, ctx_xyz, Wc1, Wq1, Wf1,
                                        Wcat, we2hi, we2lo, anchor, w1T_hi, w1T_lo);
  prep2_kernel<<<TOK / 4 + 1 + 128, 256, 0, stream>>>(Wp, bp, Wcat, be1,
                                                      wbT_hi, wbT_lo, cb,
                                                      wcatT_hi, wcatT_lo);
  build_all_kernel<<<72 + 12, 256, 0, stream>>>(ctx_xyz, noise_ctx, noise_prd, anchor,
                                                xyz_all, radmax);

  // token GEMM (split-K x4): Tpart[s] = [ctx_tok; pred_tok] @ Wbig[kslice s]
  t12_mfma_kernel<<<dim3(TROWS / 64, 2, KSPLIT), 256, 0, stream>>>(ctx_tok, pred_tok,
                                                                   wbT_hi, wbT_lo, Tpart);

  // ---- fused stage 1+2: AB assembly (all points) + knn1 + knn2 ----
  ab12_knn12_kernel<<<ABALL_BLOCKS + KNN1_BLOCKS + KNS_BLOCKS, 256, 0, stream>>>(
      Tpart, xyz_all, Wcat, cb, ctx_xyz, AB, idxA);
  conv_mfma_kernel<<<ABALL_BLOCKS, 256, 0, stream>>>(AB, idxA, we2hi, we2lo, be2, feat_in);
  offset_mfma_kernel<<<(B_ * NALL) / 64, 256, 0, stream>>>(
      feat_in,
      w1T_hi, w1T_lo, bc1, Wc2, bc2,                       // ctx set
      w1T_hi + C * C, w1T_lo + C * C, bq1, Wq2, bq2,       // pred set
      xyz_all, xyz_all, radmax);

  // ---- stage 3: global refinement ----
  pre3_knn3_kernel<<<P3G_BLOCKS + KNN3C_BLOCKS + KNN3P_BLOCKS, 256, 0, stream>>>(
      feat_in, xyz_all, Wcat, be1, wcatT_hi, wcatT_lo, ctx_xyz, anchor, radmax, AB, idx3);
  conv_mfma_kernel<<<ABALL_BLOCKS, 256, 0, stream>>>(AB, idx3, we2hi, we2lo, be2, feat_out);
  offset_mfma_kernel<<<(B_ * NALL) / 64, 256, 0, stream>>>(
      feat_out,
      w1T_hi + 2 * C * C, w1T_lo + 2 * C * C, bf1, Wf2, bf2,   // same set for all rows
      w1T_hi + 2 * C * C, w1T_lo + 2 * C * C, bf1, Wf2, bf2,
      xyz_all, out, nullptr);
}

// Round 15
// 374.021 us; speedup vs baseline: 1.0127x; 1.0127x over previous
//
#include <hip/hip_runtime.h>
#include <math.h>

// Problem constants (from setup_inputs; k==8 is fixed by the harness inputs).
constexpr int B_   = 4;
constexpr int P_   = 384;
constexpr int M_   = 64;
constexpr int TOK  = 1024;
constexpr int C    = 128;
constexpr int RC   = 12;
constexpr int RP   = 12;
constexpr int KNN  = 8;
constexpr int GS   = 12;           // group size (both ctx clusters and pred rings)
constexpr int NCTX = P_ * RC;      // 4608 ctx points per batch
constexpr int NPRD = M_ * RP;      // 768 pred points per batch
constexpr int NALL = NCTX + NPRD;  // 5376
constexpr int NG1  = NCTX / GS;    // 384 groups, stage 1
constexpr int NG3  = NALL / GS;    // 448 groups, stage 3
constexpr int TROWS = B_ * P_ + B_ * M_;  // 1792 token rows (ctx then pred)
constexpr int KSPLIT = 4;          // t12 split-K factor

// fused-grid split points
constexpr int ABALL_BLOCKS = (B_ * NALL) / 8;      // 2688 (stage-1/2 AB, global rows)
constexpr int KNN1_BLOCKS  = B_ * (NG1 / 4);       // 384
constexpr int KNS_BLOCKS   = (B_ * M_ * RP) / 256; // 12
constexpr int P3G_BLOCKS   = (B_ * NALL) / 64;     // 336 (stage-3 MFMA GEMM)
constexpr int KNN3C_BLOCKS = B_ * (NG1 / 4);       // 384 (ctx groups, wave-per-group)
constexpr int KNN3P_BLOCKS = (B_ * NPRD) / 4;      // 768 (pred queries, wave-per-query)

typedef __attribute__((ext_vector_type(8))) short bf16x8;
typedef __attribute__((ext_vector_type(4))) float f32x4;

__device__ inline unsigned short f32_to_bf16_rne(float x) {
  union { float f; unsigned int u; } v; v.f = x;
  unsigned int r = v.u + 0x7fffu + ((v.u >> 16) & 1u);
  return (unsigned short)(r >> 16);
}
__device__ inline float bf16_to_f32(unsigned short h) {
  union { float f; unsigned int u; } v; v.u = ((unsigned int)h) << 16;
  return v.f;
}
// convert 8 fp32 (two f32x4) to bf16 hi/lo fragments in registers
__device__ inline void split8(const f32x4& a0, const f32x4& a1, bf16x8& hi, bf16x8& lo) {
  float vals[8] = {a0.x, a0.y, a0.z, a0.w, a1.x, a1.y, a1.z, a1.w};
  union { unsigned short s[8]; bf16x8 v; } oh, ol;
  #pragma unroll
  for (int e = 0; e < 8; ++e) {
    unsigned short h = f32_to_bf16_rne(vals[e]);
    oh.s[e] = h;
    ol.s[e] = f32_to_bf16_rne(vals[e] - bf16_to_f32(h));
  }
  hi = oh.v; lo = ol.v;
}

// ---------------------------------------------------------------------------
// FUSED prep1: Wcat | We2 transpose | anchor | W1T transposes (Wc1/Wq1/Wf1).
__global__ __launch_bounds__(256) void prep1_kernel(const float* __restrict__ We1,
                                                    const float* __restrict__ We2,
                                                    const float* __restrict__ cxyz,
                                                    const float* __restrict__ Wc1,
                                                    const float* __restrict__ Wq1,
                                                    const float* __restrict__ Wf1,
                                                    float* __restrict__ Wcat,
                                                    unsigned short* __restrict__ we2hi,
                                                    unsigned short* __restrict__ we2lo,
                                                    float* __restrict__ anchor,
                                                    unsigned short* __restrict__ w1T_hi,
                                                    unsigned short* __restrict__ w1T_lo) {
  const int tid = threadIdx.x;
  if (blockIdx.x < 131) {
    int n = blockIdx.x * 256 + tid;
    int t = n >> 8, cc = n & 255;
    float v;
    if (cc < C) v = We1[t * C + cc] - We1[(131 + t) * C + cc];
    else        v = We1[(131 + t) * C + (cc - C)];
    Wcat[n] = v;
  } else if (blockIdx.x < 195) {
    int e = (blockIdx.x - 131) * 256 + tid;
    int n = e >> 7, k = e & 127;
    float w = We2[k * C + n];
    unsigned short h = f32_to_bf16_rne(w);
    we2hi[n * C + k] = h;
    we2lo[n * C + k] = f32_to_bf16_rne(w - bf16_to_f32(h));
  } else if (blockIdx.x == 195) {
    const int w = tid >> 6, lane = tid & 63;
    float ax = 0.f, ay = 0.f, az = 0.f;
    for (int p = lane; p < P_; p += 64) {
      const float* c = &cxyz[(w * P_ + p) * 3];
      ax += c[0]; ay += c[1]; az += c[2];
    }
    for (int o = 32; o > 0; o >>= 1) {
      ax += __shfl_down(ax, o);
      ay += __shfl_down(ay, o);
      az += __shfl_down(az, o);
    }
    if (lane == 0) {
      anchor[w * 3 + 0] = ax * (1.0f / (float)P_);
      anchor[w * 3 + 1] = ay * (1.0f / (float)P_);
      anchor[w * 3 + 2] = az * (1.0f / (float)P_);
    }
  } else {
    int e = (blockIdx.x - 196) * 256 + tid;     // 0 .. 3*16384-1
    int wsel = e >> 14, r = e & 16383;
    int c = r >> 7, k = r & 127;
    const float* W1s = (wsel == 0) ? Wc1 : (wsel == 1) ? Wq1 : Wf1;
    float w = W1s[k * C + c];
    unsigned short h = f32_to_bf16_rne(w);
    w1T_hi[(size_t)wsel * 16384 + c * 128 + k] = h;
    w1T_lo[(size_t)wsel * 16384 + c * 128 + k] = f32_to_bf16_rne(w - bf16_to_f32(h));
  }
}

// ---------------------------------------------------------------------------
// FUSED prep2: WbigT hi/lo | cb vector | WcatT hi/lo (feat part, [256][128]).
__global__ __launch_bounds__(256) void prep2_kernel(const float* __restrict__ Wp,
                                                    const float* __restrict__ bp,
                                                    const float* __restrict__ Wcat,
                                                    const float* __restrict__ be1,
                                                    unsigned short* __restrict__ wbT_hi,
                                                    unsigned short* __restrict__ wbT_lo,
                                                    float* __restrict__ cb,
                                                    unsigned short* __restrict__ wcatT_hi,
                                                    unsigned short* __restrict__ wcatT_lo) {
  __shared__ float s_lds[4][128];
  const int tid = threadIdx.x;
  if (blockIdx.x < TOK / 4) {
    const int k0 = blockIdx.x * 4;
    for (int l = tid; l < 4 * 128; l += 256) {
      int r = l >> 7, f = l & 127;
      s_lds[r][f] = Wp[(k0 + r) * C + f];
    }
    __syncthreads();
    float acc[4] = {0.f, 0.f, 0.f, 0.f};
    #pragma unroll 4
    for (int f = 0; f < 128; ++f) {
      float wv = Wcat[f * 256 + tid];
      #pragma unroll
      for (int r = 0; r < 4; ++r) acc[r] = fmaf(s_lds[r][f], wv, acc[r]);
    }
    #pragma unroll
    for (int r = 0; r < 4; ++r) {
      unsigned short h = f32_to_bf16_rne(acc[r]);
      wbT_hi[(size_t)tid * TOK + k0 + r] = h;
      wbT_lo[(size_t)tid * TOK + k0 + r] = f32_to_bf16_rne(acc[r] - bf16_to_f32(h));
    }
  } else if (blockIdx.x == TOK / 4) {
    if (tid < 128) s_lds[0][tid] = bp[tid];
    __syncthreads();
    float a = (tid < 128) ? be1[tid] : 0.f;
    #pragma unroll 4
    for (int f = 0; f < 128; ++f) a = fmaf(s_lds[0][f], Wcat[f * 256 + tid], a);
    cb[tid] = a;
  } else {
    int e = (blockIdx.x - TOK / 4 - 1) * 256 + tid;   // 0 .. 256*128-1
    int c = e >> 7, k = e & 127;
    float w = Wcat[k * 256 + c];
    unsigned short h = f32_to_bf16_rne(w);
    wcatT_hi[c * 128 + k] = h;
    wcatT_lo[c * 128 + k] = f32_to_bf16_rne(w - bf16_to_f32(h));
  }
}

// ---------------------------------------------------------------------------
// FUSED geometry build: ctx points (+radmax zero-init) | pred points.
__global__ __launch_bounds__(256) void build_all_kernel(const float* __restrict__ cxyz,
                                                        const float* __restrict__ noise_c,
                                                        const float* __restrict__ noise_p,
                                                        const float* __restrict__ anchor,
                                                        float* __restrict__ xyz_all,
                                                        int* __restrict__ radmax) {
  if (blockIdx.x < 72) {
    int n = blockIdx.x * 256 + threadIdx.x;
    if (n < B_ * NG3) radmax[n] = 0;      // float 0.0 bits
    int b = n / NCTX, i = n % NCTX, p = i / RC;
    float x = noise_c[n * 3 + 0], y = noise_c[n * 3 + 1], z = noise_c[n * 3 + 2];
    float s = 0.02f / (sqrtf(x * x + y * y + z * z) + 1e-6f);
    const float* c = &cxyz[(b * P_ + p) * 3];
    float* o = &xyz_all[(b * NALL + i) * 3];
    o[0] = c[0] + x * s;
    o[1] = c[1] + y * s;
    o[2] = c[2] + z * s;
  } else {
    int n = (blockIdx.x - 72) * 256 + threadIdx.x;
    int b = n / NPRD, i = n % NPRD;
    float x = noise_p[n * 3 + 0], y = noise_p[n * 3 + 1], z = noise_p[n * 3 + 2];
    float s = 0.05f / (sqrtf(x * x + y * y + z * z) + 1e-6f);
    const float* a = &anchor[b * 3];
    float* o = &xyz_all[(b * NALL + NCTX + i) * 3];
    o[0] = a[0] + x * s;
    o[1] = a[1] + y * s;
    o[2] = a[2] + z * s;
  }
}

// ---------------------------------------------------------------------------
// Tpart[s][row][c] = tok[row] @ Wbig[kslice s]. Split-bf16 MFMA GEMM, split-K.
__global__ __launch_bounds__(256) void t12_mfma_kernel(const float* __restrict__ ctx_tok,
                                                       const float* __restrict__ pred_tok,
                                                       const unsigned short* __restrict__ wbT_hi,
                                                       const unsigned short* __restrict__ wbT_lo,
                                                       float* __restrict__ Tpart) {
  __shared__ unsigned short ahi[64 * 128];   // 16 KB
  __shared__ unsigned short alo[64 * 128];   // 16 KB
  __shared__ unsigned short bhi[128 * 128];  // 32 KB
  const int tid = threadIdx.x;
  const int r0 = blockIdx.x * 64;
  const int n0 = blockIdx.y * 128;
  const int s  = blockIdx.z;
  const float* src = (r0 < B_ * P_) ? (ctx_tok + (size_t)r0 * TOK)
                                    : (pred_tok + (size_t)(r0 - B_ * P_) * TOK);
  const int lane = tid & 63, w = tid >> 6;
  const int m = lane & 15, quad = lane >> 4;

  f32x4 acc[8];
  #pragma unroll
  for (int nt = 0; nt < 8; ++nt) acc[nt] = (f32x4){0.f, 0.f, 0.f, 0.f};

  #pragma unroll 1
  for (int kc = s * (8 / KSPLIT); kc < (s + 1) * (8 / KSPLIT); ++kc) {
    __syncthreads();
    #pragma unroll
    for (int i = 0; i < 4; ++i) {
      int task = tid + 256 * i;           // 0..1023
      int r = task >> 4, c = task & 15;
      const float* sp = src + (size_t)r * TOK + kc * 128 + c * 8;
      f32x4 a0 = *(const f32x4*)sp;
      f32x4 a1 = *(const f32x4*)(sp + 4);
      bf16x8 oh, ol;
      split8(a0, a1, oh, ol);
      int dst = (r * 16 + (c ^ (r & 15))) * 8;
      *(bf16x8*)(ahi + dst) = oh;
      *(bf16x8*)(alo + dst) = ol;
    }
    #pragma unroll
    for (int i = 0; i < 8; ++i) {
      int task = tid + 256 * i;           // 0..2047
      int n = task >> 4, c = task & 15;
      f32x4 v = *(const f32x4*)(wbT_hi + (size_t)(n0 + n) * TOK + kc * 128 + c * 8);
      *(f32x4*)(bhi + (n * 16 + (c ^ (n & 15))) * 8) = v;
    }
    __syncthreads();
    #pragma unroll
    for (int ks = 0; ks < 4; ++ks) {
      int c0 = ks * 4 + quad;
      int aoff = ((w * 16 + m) * 16 + (c0 ^ m)) * 8;
      bf16x8 av  = *(const bf16x8*)(ahi + aoff);
      bf16x8 av2 = *(const bf16x8*)(alo + aoff);
      #pragma unroll
      for (int nt = 0; nt < 8; ++nt) {
        int n = nt * 16 + m;
        bf16x8 bh = *(const bf16x8*)(bhi + (n * 16 + (c0 ^ m)) * 8);
        bf16x8 bl = *(const bf16x8*)(wbT_lo + (size_t)(n0 + n) * TOK + kc * 128 + c0 * 8);
        acc[nt] = __builtin_amdgcn_mfma_f32_16x16x32_bf16(av, bh, acc[nt], 0, 0, 0);
        acc[nt] = __builtin_amdgcn_mfma_f32_16x16x32_bf16(av, bl, acc[nt], 0, 0, 0);
        acc[nt] = __builtin_amdgcn_mfma_f32_16x16x32_bf16(av2, bh, acc[nt], 0, 0, 0);
      }
    }
  }
  #pragma unroll
  for (int nt = 0; nt < 8; ++nt) {
    int col = n0 + nt * 16 + m;
    #pragma unroll
    for (int reg = 0; reg < 4; ++reg) {
      int row = r0 + w * 16 + quad * 4 + reg;
      Tpart[((size_t)s * TROWS + row) * 256 + col] = acc[nt][reg];
    }
  }
}

// ---------------------------------------------------------------------------
// Wave-per-group kNN body for CTX groups. Outputs GLOBAL point rows.
template <int STAGE>
__device__ __forceinline__ void knn_wave_body(
    const float* __restrict__ xyz_all, const float* __restrict__ ctx_xyz,
    const float* __restrict__ anchor, const int* __restrict__ radmax,
    int b, int p, int lane,
    float4* own, int* gl, float4* tile, int* tilei,
    int* __restrict__ idx_out) {
  const int NG  = (STAGE == 1) ? NG1 : NG3;
  const float* base = xyz_all + (size_t)b * NALL * 3;
  const float* cxb  = ctx_xyz + (size_t)b * P_ * 3;
  const bool owner = lane < GS;
  const int qloc = p * GS + lane;

  auto sph = [&](int g) -> float4 {
    float4 c;
    float rad;
    if (STAGE == 1) {
      c = make_float4(cxb[g * 3 + 0], cxb[g * 3 + 1], cxb[g * 3 + 2], 0.f);
      rad = 0.0201f;
    } else {
      float moff = __int_as_float(radmax[b * NG3 + g]);
      if (g < NG1) {
        c = make_float4(cxb[g * 3 + 0], cxb[g * 3 + 1], cxb[g * 3 + 2], 0.f);
        rad = 0.0201f + moff * 1.0002f + 1e-6f;
      } else {
        c = make_float4(anchor[b * 3 + 0], anchor[b * 3 + 1], anchor[b * 3 + 2], 0.f);
        rad = 0.0501f + moff * 1.0002f + 1e-6f;
      }
    }
    c.w = rad;
    return c;
  };

  if (owner) {
    float x = base[qloc * 3 + 0], y = base[qloc * 3 + 1], z = base[qloc * 3 + 2];
    own[lane] = make_float4(x, y, z, x * x + y * y + z * z);
  }
  float qx = 0.f, qy = 0.f, qz = 0.f, sqi = 0.f;
  if (owner) {
    float4 q = own[lane];
    qx = q.x; qy = q.y; qz = q.z; sqi = q.w;
  }

  float bd[KNN];
  int   bi[KNN];
  #pragma unroll
  for (int u = 0; u < KNN; ++u) { bd[u] = 3e38f; bi[u] = 0x7fffffff; }

  #pragma unroll 1
  for (int j = 0; j < GS; ++j) {
    float4 cj = own[j];
    float d2 = sqi + cj.w - 2.0f * (qx * cj.x + qy * cj.y + qz * cj.z);
    if (owner && j != lane && d2 < bd[KNN - 1]) {
      bd[KNN - 1] = d2; bi[KNN - 1] = p * GS + j;
      #pragma unroll
      for (int u = KNN - 1; u > 0; --u) {
        if (bd[u] < bd[u - 1]) {
          float td = bd[u]; bd[u] = bd[u - 1]; bd[u - 1] = td;
          int   ti = bi[u]; bi[u] = bi[u - 1]; bi[u - 1] = ti;
        }
      }
    }
  }

  float t = owner ? bd[KNN - 1] : 0.f;
  #pragma unroll
  for (int mm = 1; mm < 64; mm <<= 1) t = fmaxf(t, __shfl_xor(t, mm));
  float r = sqrtf(fmaxf(t, 0.f)) * 1.001f + 1e-6f;

  const float4 gp = sph(p);
  const float rlim = r + gp.w;

  int ng = 0;
  #pragma unroll 1
  for (int gs0 = 0; gs0 < NG; gs0 += 64) {
    int g = gs0 + lane;
    bool ok = false;
    if (g < NG && g != p) {
      float4 gq = sph(g);
      float dx = gq.x - gp.x, dy = gq.y - gp.y, dz = gq.z - gp.z;
      float lim = rlim + gq.w;
      ok = (dx * dx + dy * dy + dz * dz) < lim * lim * 1.001f;
    }
    unsigned long long mask = __ballot(ok);
    if (ok) gl[ng + (int)__popcll(mask & ((1ull << lane) - 1ull))] = g;
    ng += (int)__popcll(mask);
  }

  const int total = ng * GS;
  #pragma unroll 1
  for (int cs = 0; cs < total; cs += 64) {
    int ci = cs + lane;
    if (ci < total) {
      int gg = gl[ci / GS];
      int j  = ci % GS;
      int jloc = gg * GS + j;
      float x = base[jloc * 3 + 0], y = base[jloc * 3 + 1], z = base[jloc * 3 + 2];
      tile[lane] = make_float4(x, y, z, x * x + y * y + z * z);
      tilei[lane] = jloc;
    }
    int nj = min(64, total - cs);
    #pragma unroll 1
    for (int jj = 0; jj < nj; ++jj) {
      float4 tt = tile[jj];
      int ti0 = tilei[jj];
      float d2 = sqi + tt.w - 2.0f * (qx * tt.x + qy * tt.y + qz * tt.z);
      if (owner && d2 < bd[KNN - 1]) {
        bd[KNN - 1] = d2; bi[KNN - 1] = ti0;
        #pragma unroll
        for (int u = KNN - 1; u > 0; --u) {
          if (bd[u] < bd[u - 1]) {
            float td = bd[u]; bd[u] = bd[u - 1]; bd[u - 1] = td;
            int   ti = bi[u]; bi[u] = bi[u - 1]; bi[u - 1] = ti;
          }
        }
      }
    }
  }

  if (owner) {
    int gid = b * NALL + qloc;            // GLOBAL point row
    #pragma unroll
    for (int u = 0; u < KNN; ++u) idx_out[gid * KNN + u] = b * NALL + bi[u];
  }
}

// ---------------------------------------------------------------------------
// Wave-per-QUERY kNN for stage-3 PRED points (lane-partitioned scan + merge).
__device__ __forceinline__ void knn3_pred_wave(
    const float* __restrict__ xyz_all, const float* __restrict__ ctx_xyz,
    const float* __restrict__ anchor, const int* __restrict__ radmax,
    int b, int q, int lane, int* gl, int* __restrict__ idx_out) {
  const float* base = xyz_all + (size_t)b * NALL * 3;
  const float* cxb  = ctx_xyz + (size_t)b * P_ * 3;
  const int qloc = NCTX + q;
  const int p = NG1 + q / GS;

  const float qx = base[qloc * 3 + 0], qy = base[qloc * 3 + 1], qz = base[qloc * 3 + 2];
  const float sqi = qx * qx + qy * qy + qz * qz;

  float dcur = 3e38f;
  int   icur = 0x7fffffff;
  if (lane < GS) {
    int jloc = p * GS + lane;
    if (jloc != qloc) {
      float x = base[jloc * 3 + 0], y = base[jloc * 3 + 1], z = base[jloc * 3 + 2];
      dcur = sqi + (x * x + y * y + z * z) - 2.0f * (qx * x + qy * y + qz * z);
      icur = jloc;
    }
  }
  float t = 3e38f;
  #pragma unroll 1
  for (int r8 = 0; r8 < KNN; ++r8) {
    float d = dcur; int i = icur;
    #pragma unroll
    for (int mm = 1; mm < 64; mm <<= 1) {
      float od = __shfl_xor(d, mm);
      int   oi = __shfl_xor(i, mm);
      if (od < d || (od == d && oi < i)) { d = od; i = oi; }
    }
    t = d;
    if (icur == i) { dcur = 3e38f; icur = 0x7fffffff; }
  }
  float r = sqrtf(fmaxf(t, 0.f)) * 1.001f + 1e-6f;

  int ng = 0;
  #pragma unroll 1
  for (int gs0 = 0; gs0 < NG3; gs0 += 64) {
    int g = gs0 + lane;
    bool ok = false;
    if (g < NG3) {
      float cx, cy, cz, rad;
      float moff = __int_as_float(radmax[b * NG3 + g]) * 1.0002f + 1e-6f;
      if (g < NG1) {
        cx = cxb[g * 3 + 0]; cy = cxb[g * 3 + 1]; cz = cxb[g * 3 + 2];
        rad = 0.0201f + moff;
      } else {
        cx = anchor[b * 3 + 0]; cy = anchor[b * 3 + 1]; cz = anchor[b * 3 + 2];
        rad = 0.0501f + moff;
      }
      float dx = cx - qx, dy = cy - qy, dz = cz - qz;
      float lim = r + rad;
      ok = (dx * dx + dy * dy + dz * dz) < lim * lim * 1.001f;
    }
    unsigned long long mask = __ballot(ok);
    if (ok) gl[ng + (int)__popcll(mask & ((1ull << lane) - 1ull))] = g;
    ng += (int)__popcll(mask);
  }

  float bd[KNN];
  int   bi[KNN];
  #pragma unroll
  for (int u = 0; u < KNN; ++u) { bd[u] = 3e38f; bi[u] = 0x7fffffff; }
  const int total = ng * GS;
  #pragma unroll 2
  for (int ci = lane; ci < total; ci += 64) {
    int gg = gl[ci / GS];
    int j  = ci % GS;
    int jloc = gg * GS + j;
    float x = base[jloc * 3 + 0], y = base[jloc * 3 + 1], z = base[jloc * 3 + 2];
    float d2 = sqi + (x * x + y * y + z * z) - 2.0f * (qx * x + qy * y + qz * z);
    if (jloc != qloc && d2 < bd[KNN - 1]) {
      bd[KNN - 1] = d2; bi[KNN - 1] = jloc;
      #pragma unroll
      for (int u = KNN - 1; u > 0; --u) {
        if (bd[u] < bd[u - 1]) {
          float td = bd[u]; bd[u] = bd[u - 1]; bd[u - 1] = td;
          int   ti = bi[u]; bi[u] = bi[u - 1]; bi[u - 1] = ti;
        }
      }
    }
  }

  const int gid = b * NALL + qloc;
  #pragma unroll 1
  for (int r8 = 0; r8 < KNN; ++r8) {
    float d = bd[0]; int i = bi[0];
    #pragma unroll
    for (int mm = 1; mm < 64; mm <<= 1) {
      float od = __shfl_xor(d, mm);
      int   oi = __shfl_xor(i, mm);
      if (od < d || (od == d && oi < i)) { d = od; i = oi; }
    }
    if (lane == 0) idx_out[gid * KNN + r8] = b * NALL + i;
    if (bi[0] == i) {
      #pragma unroll
      for (int u = 0; u < KNN - 1; ++u) { bd[u] = bd[u + 1]; bi[u] = bi[u + 1]; }
      bd[KNN - 1] = 3e38f; bi[KNN - 1] = 0x7fffffff;
    }
  }
}

// ---------------------------------------------------------------------------
// FUSED stage-1/2: AB assembly for ALL points (global-row layout) + stage-1
// ctx-group kNN + stage-2 small kNN. idxA holds GLOBAL point rows.
__global__ __launch_bounds__(256) void ab12_knn12_kernel(
    const float* __restrict__ Tp, const float* __restrict__ xyz_all,
    const float* __restrict__ Wcat, const float* __restrict__ cb,
    const float* __restrict__ ctx_xyz,
    float* __restrict__ AB, int* __restrict__ idxA) {
  __shared__ float4 own[4][GS];
  __shared__ int    gl[4][NG1];
  __shared__ float4 tile[4][64];
  __shared__ int    tilei[4][64];
  const int tid = threadIdx.x;
  if (blockIdx.x < ABALL_BLOCKS) {
    const int base = blockIdx.x * 8;
    const float wx = Wcat[128 * 256 + tid];
    const float wy = Wcat[129 * 256 + tid];
    const float wz = Wcat[130 * 256 + tid];
    const float cbv = cb[tid];
    #pragma unroll
    for (int p = 0; p < 8; ++p) {
      int n = base + p;                  // global point row
      int b = n / NALL, row = n % NALL;
      int trow = (row < NCTX) ? (b * (NCTX / GS) + row / GS)
                              : (B_ * P_ + b * (NPRD / GS) + (row - NCTX) / GS);
      const float* xr = xyz_all + (size_t)n * 3;
      float x = xr[0], y = xr[1], z = xr[2];
      float v = cbv;
      #pragma unroll
      for (int s = 0; s < KSPLIT; ++s)
        v += Tp[((size_t)s * TROWS + trow) * 256 + tid];
      v = fmaf(x, wx, v);
      v = fmaf(y, wy, v);
      v = fmaf(z, wz, v);
      AB[(size_t)n * 256 + tid] = v;
    }
  } else if (blockIdx.x < ABALL_BLOCKS + KNN1_BLOCKS) {
    int kblk = blockIdx.x - ABALL_BLOCKS;
    int w = tid >> 6, lane = tid & 63;
    int b = kblk / (NG1 / 4);
    int p = (kblk % (NG1 / 4)) * 4 + w;
    knn_wave_body<1>(xyz_all, ctx_xyz, nullptr, nullptr, b, p, lane,
                     own[w], gl[w], tile[w], tilei[w], idxA);
  } else {
    int q = (blockIdx.x - ABALL_BLOCKS - KNN1_BLOCKS) * 256 + tid;  // 0..3071
    int gr = q / RP, qi = q % RP;
    int b = gr / M_, w = gr % M_;
    const float* base = xyz_all + (size_t)(b * NALL + NCTX + w * RP) * 3;
    float cx[RP], cy[RP], cz[RP], cs[RP];
    #pragma unroll
    for (int j = 0; j < RP; ++j) {
      cx[j] = base[j * 3 + 0]; cy[j] = base[j * 3 + 1]; cz[j] = base[j * 3 + 2];
      cs[j] = cx[j] * cx[j] + cy[j] * cy[j] + cz[j] * cz[j];
    }
    float qx = cx[0], qy = cy[0], qz = cz[0], sqi = cs[0];
    #pragma unroll
    for (int j = 0; j < RP; ++j) {
      if (j == qi) { qx = cx[j]; qy = cy[j]; qz = cz[j]; sqi = cs[j]; }
    }
    float bd[KNN];
    int   bi[KNN];
    #pragma unroll
    for (int u = 0; u < KNN; ++u) { bd[u] = 3e38f; bi[u] = 0; }
    #pragma unroll
    for (int j = 0; j < RP; ++j) {
      float d2 = sqi + cs[j] - 2.0f * (qx * cx[j] + qy * cy[j] + qz * cz[j]);
      if (j != qi && d2 < bd[KNN - 1]) {
        bd[KNN - 1] = d2; bi[KNN - 1] = j;
        #pragma unroll
        for (int u = KNN - 1; u > 0; --u) {
          if (bd[u] < bd[u - 1]) {
            float td = bd[u]; bd[u] = bd[u - 1]; bd[u - 1] = td;
            int   ti = bi[u]; bi[u] = bi[u - 1]; bi[u - 1] = ti;
          }
        }
      }
    }
    int gid = b * NALL + NCTX + w * RP + qi;
    #pragma unroll
    for (int u = 0; u < KNN; ++u)
      idxA[gid * KNN + u] = b * NALL + NCTX + w * RP + bi[u];
  }
}

// ---------------------------------------------------------------------------
// FUSED: stage-3 precompute as LDS-free MFMA GEMM | ctx-group kNN | pred kNN.
__global__ __launch_bounds__(256) void pre3_knn3_kernel(
    const float* __restrict__ feat, const float* __restrict__ xyz_all,
    const float* __restrict__ Wcat, const float* __restrict__ be1,
    const unsigned short* __restrict__ wcatT_hi, const unsigned short* __restrict__ wcatT_lo,
    const float* __restrict__ ctx_xyz, const float* __restrict__ anchor,
    const int* __restrict__ radmax,
    float* __restrict__ AB, int* __restrict__ idx3) {
  __shared__ float4 own[4][GS];
  __shared__ int    gl[4][NG3];
  __shared__ float4 tile[4][64];
  __shared__ int    tilei[4][64];
  const int tid = threadIdx.x;
  if (blockIdx.x < P3G_BLOCKS) {
    const int lane = tid & 63, w = tid >> 6;
    const int m = lane & 15, quad = lane >> 4;
    const int r0 = blockIdx.x * 64;
    const float* arow = feat + (size_t)(r0 + w * 16 + m) * C;

    f32x4 acc[16];
    #pragma unroll
    for (int nt = 0; nt < 16; ++nt) acc[nt] = (f32x4){0.f, 0.f, 0.f, 0.f};

    #pragma unroll
    for (int ks = 0; ks < 4; ++ks) {
      int k0 = ks * 32 + quad * 8;
      f32x4 a0 = *(const f32x4*)(arow + k0);
      f32x4 a1 = *(const f32x4*)(arow + k0 + 4);
      bf16x8 ahi, alo;
      split8(a0, a1, ahi, alo);
      #pragma unroll
      for (int nt = 0; nt < 16; ++nt) {
        int n = nt * 16 + m;
        bf16x8 bh = *(const bf16x8*)(wcatT_hi + n * 128 + k0);
        bf16x8 bl = *(const bf16x8*)(wcatT_lo + n * 128 + k0);
        acc[nt] = __builtin_amdgcn_mfma_f32_16x16x32_bf16(ahi, bh, acc[nt], 0, 0, 0);
        acc[nt] = __builtin_amdgcn_mfma_f32_16x16x32_bf16(ahi, bl, acc[nt], 0, 0, 0);
        acc[nt] = __builtin_amdgcn_mfma_f32_16x16x32_bf16(alo, bh, acc[nt], 0, 0, 0);
      }
    }
    float xr[4], yr[4], zr[4];
    #pragma unroll
    for (int reg = 0; reg < 4; ++reg) {
      int row = r0 + w * 16 + quad * 4 + reg;
      xr[reg] = xyz_all[row * 3 + 0];
      yr[reg] = xyz_all[row * 3 + 1];
      zr[reg] = xyz_all[row * 3 + 2];
    }
    #pragma unroll
    for (int nt = 0; nt < 16; ++nt) {
      int col = nt * 16 + m;
      float cbv = (col < C) ? be1[col] : 0.0f;
      float wx = Wcat[128 * 256 + col];
      float wy = Wcat[129 * 256 + col];
      float wz = Wcat[130 * 256 + col];
      #pragma unroll
      for (int reg = 0; reg < 4; ++reg) {
        int row = r0 + w * 16 + quad * 4 + reg;
        float v = acc[nt][reg] + cbv;
        v = fmaf(xr[reg], wx, v);
        v = fmaf(yr[reg], wy, v);
        v = fmaf(zr[reg], wz, v);
        AB[(size_t)row * 256 + col] = v;
      }
    }
  } else if (blockIdx.x < P3G_BLOCKS + KNN3C_BLOCKS) {
    int kblk = blockIdx.x - P3G_BLOCKS;
    int w = tid >> 6, lane = tid & 63;
    int b = kblk / (NG1 / 4);
    int p = (kblk % (NG1 / 4)) * 4 + w;     // ctx groups only: p < NG1
    knn_wave_body<3>(xyz_all, ctx_xyz, anchor, radmax, b, p, lane,
                     own[w], gl[w], tile[w], tilei[w], idx3);
  } else {
    int kblk = blockIdx.x - P3G_BLOCKS - KNN3C_BLOCKS;
    int w = tid >> 6, lane = tid & 63;
    int wid = kblk * 4 + w;                  // 0 .. B*NPRD-1
    int b = wid / NPRD, q = wid % NPRD;
    knn3_pred_wave(xyz_all, ctx_xyz, anchor, radmax, b, q, lane, gl[w], idx3);
  }
}

// ---------------------------------------------------------------------------
// MFMA EdgeConv core (round-13 proven form: h hi/lo + We2-hi in LDS, We2-lo
// streamed from global; split-bf16, 3 MFMAs, ~2^-16 err) + XCD-contiguous
// block swizzle (measured in r14: halves FETCH_SIZE via per-XCD L2 locality).
__global__ __launch_bounds__(256) void conv_mfma_kernel(const float* __restrict__ AB,
                                                        const int* __restrict__ idx,
                                                        const unsigned short* __restrict__ w2hi_g,
                                                        const unsigned short* __restrict__ w2lo_g,
                                                        const float* __restrict__ be2,
                                                        float* __restrict__ feat_out) {
  __shared__ unsigned short hhi[64 * 128];    // 16 KB
  __shared__ unsigned short hlo[64 * 128];    // 16 KB
  __shared__ unsigned short w2hi[128 * 128];  // 32 KB
  const int tid = threadIdx.x;
  // XCD-contiguous swizzle (grid = 2688, divisible by 8; bijective remap):
  // consecutive AB slices land on one XCD's L2 instead of round-robining.
  const int nb = gridDim.x;
  const int blk = (blockIdx.x % 8) * (nb / 8) + (blockIdx.x / 8);
  const int base = blk * 8;

  #pragma unroll
  for (int i = 0; i < 8; ++i) {
    int q = tid + 256 * i;
    int n = q >> 4, c = q & 15;
    f32x4 v = *(const f32x4*)(w2hi_g + n * 128 + c * 8);
    *(f32x4*)(w2hi + (n * 16 + (c ^ (n & 15))) * 8) = v;
  }

  #pragma unroll
  for (int i = 0; i < 4; ++i) {
    int task = tid + 256 * i;
    int r = task >> 4, c = task & 15;
    int p = r >> 3, nb2 = r & 7;
    int g = base + p;
    int j = idx[g * KNN + nb2];
    const float* aP = AB + (size_t)g * 256 + c * 8;
    const float* bP = AB + (size_t)j * 256 + 128 + c * 8;
    f32x4 a0 = *(const f32x4*)aP;
    f32x4 a1 = *(const f32x4*)(aP + 4);
    f32x4 b0 = *(const f32x4*)bP;
    f32x4 b1 = *(const f32x4*)(bP + 4);
    f32x4 s0 = {fmaxf(a0.x + b0.x, 0.f), fmaxf(a0.y + b0.y, 0.f),
                fmaxf(a0.z + b0.z, 0.f), fmaxf(a0.w + b0.w, 0.f)};
    f32x4 s1 = {fmaxf(a1.x + b1.x, 0.f), fmaxf(a1.y + b1.y, 0.f),
                fmaxf(a1.z + b1.z, 0.f), fmaxf(a1.w + b1.w, 0.f)};
    bf16x8 oh, ol;
    split8(s0, s1, oh, ol);
    int dst = (r * 16 + (c ^ (r & 15))) * 8;
    *(bf16x8*)(hhi + dst) = oh;
    *(bf16x8*)(hlo + dst) = ol;
  }
  __syncthreads();

  const int lane = tid & 63, w = tid >> 6;
  const int m = lane & 15, quad = lane >> 4;
  f32x4 acc[8];
  #pragma unroll
  for (int nt = 0; nt < 8; ++nt) acc[nt] = (f32x4){0.f, 0.f, 0.f, 0.f};

  #pragma unroll 1
  for (int ks = 0; ks < 4; ++ks) {
    int c0 = ks * 4 + quad;
    int k0 = c0 * 8;
    int rowA = w * 16 + m;
    int aoff = (rowA * 16 + (c0 ^ m)) * 8;
    bf16x8 ahi = *(const bf16x8*)(hhi + aoff);
    bf16x8 alo = *(const bf16x8*)(hlo + aoff);
    #pragma unroll
    for (int nt = 0; nt < 8; ++nt) {
      int n = nt * 16 + m;
      bf16x8 bhi = *(const bf16x8*)(w2hi + (n * 16 + (c0 ^ m)) * 8);
      bf16x8 blo = *(const bf16x8*)(w2lo_g + n * 128 + k0);
      acc[nt] = __builtin_amdgcn_mfma_f32_16x16x32_bf16(ahi, bhi, acc[nt], 0, 0, 0);
      acc[nt] = __builtin_amdgcn_mfma_f32_16x16x32_bf16(ahi, blo, acc[nt], 0, 0, 0);
      acc[nt] = __builtin_amdgcn_mfma_f32_16x16x32_bf16(alo, bhi, acc[nt], 0, 0, 0);
    }
  }

  int pt = 2 * w + (quad >> 1);
  int g = base + pt;                         // global point row
  float* orow = feat_out + (size_t)g * C;
  bool writer = (quad & 1) == 0;
  #pragma unroll
  for (int nt = 0; nt < 8; ++nt) {
    float v = fmaxf(fmaxf(acc[nt].x, acc[nt].y), fmaxf(acc[nt].z, acc[nt].w));
    v = fmaxf(v, __shfl_xor(v, 16));
    if (writer) {
      int col = nt * 16 + m;
      orow[col] = v + be2[col];
    }
  }
}

// ---------------------------------------------------------------------------
// MFMA offset MLP over global rows with per-block weight-set selection.
__global__ __launch_bounds__(256) void offset_mfma_kernel(
    const float* __restrict__ feat,
    const unsigned short* __restrict__ w1T_hi_c, const unsigned short* __restrict__ w1T_lo_c,
    const float* __restrict__ b1_c, const float* __restrict__ W2_c, const float* __restrict__ b2_c,
    const unsigned short* __restrict__ w1T_hi_p, const unsigned short* __restrict__ w1T_lo_p,
    const float* __restrict__ b1_p, const float* __restrict__ W2_p, const float* __restrict__ b2_p,
    const float* __restrict__ xyz_in, float* __restrict__ xyz_out,
    int* __restrict__ radmax) {
  const int tid = threadIdx.x;
  const int lane = tid & 63, w = tid >> 6;
  const int m = lane & 15, quad = lane >> 4;
  const int r0 = blockIdx.x * 64;            // global point base
  const bool isCtx = (r0 % NALL) < NCTX;

  const unsigned short* w1T_hi = isCtx ? w1T_hi_c : w1T_hi_p;
  const unsigned short* w1T_lo = isCtx ? w1T_lo_c : w1T_lo_p;
  const float* b1 = isCtx ? b1_c : b1_p;
  const float* W2 = isCtx ? W2_c : W2_p;
  const float* b2 = isCtx ? b2_c : b2_p;

  const float* arow = feat + (size_t)(r0 + w * 16 + m) * C;

  f32x4 acc[8];
  #pragma unroll
  for (int nt = 0; nt < 8; ++nt) acc[nt] = (f32x4){0.f, 0.f, 0.f, 0.f};

  #pragma unroll
  for (int ks = 0; ks < 4; ++ks) {
    int k0 = ks * 32 + quad * 8;
    f32x4 a0 = *(const f32x4*)(arow + k0);
    f32x4 a1 = *(const f32x4*)(arow + k0 + 4);
    bf16x8 ahi, alo;
    split8(a0, a1, ahi, alo);
    #pragma unroll
    for (int nt = 0; nt < 8; ++nt) {
      int n = nt * 16 + m;
      bf16x8 bh = *(const bf16x8*)(w1T_hi + n * 128 + k0);
      bf16x8 bl = *(const bf16x8*)(w1T_lo + n * 128 + k0);
      acc[nt] = __builtin_amdgcn_mfma_f32_16x16x32_bf16(ahi, bh, acc[nt], 0, 0, 0);
      acc[nt] = __builtin_amdgcn_mfma_f32_16x16x32_bf16(ahi, bl, acc[nt], 0, 0, 0);
      acc[nt] = __builtin_amdgcn_mfma_f32_16x16x32_bf16(alo, bh, acc[nt], 0, 0, 0);
    }
  }

  float p0[4] = {0.f, 0.f, 0.f, 0.f};
  float p1[4] = {0.f, 0.f, 0.f, 0.f};
  float p2[4] = {0.f, 0.f, 0.f, 0.f};
  #pragma unroll
  for (int nt = 0; nt < 8; ++nt) {
    int col = nt * 16 + m;
    float b1v = b1[col];
    float w20 = W2[col * 3 + 0], w21 = W2[col * 3 + 1], w22 = W2[col * 3 + 2];
    #pragma unroll
    for (int reg = 0; reg < 4; ++reg) {
      float h = fmaxf(acc[nt][reg] + b1v, 0.0f);
      p0[reg] = fmaf(h, w20, p0[reg]);
      p1[reg] = fmaf(h, w21, p1[reg]);
      p2[reg] = fmaf(h, w22, p2[reg]);
    }
  }
  #pragma unroll
  for (int o = 1; o < 16; o <<= 1) {
    #pragma unroll
    for (int reg = 0; reg < 4; ++reg) {
      p0[reg] += __shfl_xor(p0[reg], o);
      p1[reg] += __shfl_xor(p1[reg], o);
      p2[reg] += __shfl_xor(p2[reg], o);
    }
  }
  if (m == 0) {
    float b20 = b2[0], b21 = b2[1], b22 = b2[2];
    #pragma unroll
    for (int reg = 0; reg < 4; ++reg) {
      int nO = r0 + w * 16 + quad * 4 + reg;   // global point row
      int row = nO * 3;
      float o0 = p0[reg] + b20;
      float o1 = p1[reg] + b21;
      float o2 = p2[reg] + b22;
      xyz_out[row + 0] = xyz_in[row + 0] + o0;
      xyz_out[row + 1] = xyz_in[row + 1] + o1;
      xyz_out[row + 2] = xyz_in[row + 2] + o2;
      if (radmax != nullptr) {
        int b = nO / NALL, loc = nO % NALL;
        float mag = sqrtf(o0 * o0 + o1 * o1 + o2 * o2);
        atomicMax(radmax + b * NG3 + loc / GS, __float_as_int(mag));
      }
    }
  }
}

// ---------------------------------------------------------------------------
extern "C" void kernel_launch(void* const* d_in, const int* in_sizes, int n_in,
                              void* d_out, int out_size, void* d_ws, size_t ws_size,
                              hipStream_t stream) {
  (void)in_sizes; (void)n_in; (void)out_size; (void)ws_size;
  const float* ctx_xyz   = (const float*)d_in[0];
  const float* ctx_tok   = (const float*)d_in[1];
  const float* pred_tok  = (const float*)d_in[2];
  const float* noise_ctx = (const float*)d_in[3];
  const float* noise_prd = (const float*)d_in[4];
  const float* Wp  = (const float*)d_in[5];
  const float* bp  = (const float*)d_in[6];
  const float* We1 = (const float*)d_in[7];
  const float* be1 = (const float*)d_in[8];
  const float* We2 = (const float*)d_in[9];
  const float* be2 = (const float*)d_in[10];
  const float* Wc1 = (const float*)d_in[11];
  const float* bc1 = (const float*)d_in[12];
  const float* Wc2 = (const float*)d_in[13];
  const float* bc2 = (const float*)d_in[14];
  const float* Wq1 = (const float*)d_in[15];
  const float* bq1 = (const float*)d_in[16];
  const float* Wq2 = (const float*)d_in[17];
  const float* bq2 = (const float*)d_in[18];
  const float* Wf1 = (const float*)d_in[19];
  const float* bf1 = (const float*)d_in[20];
  const float* Wf2 = (const float*)d_in[21];
  const float* bf2 = (const float*)d_in[22];
  float* out = (float*)d_out;

  // workspace layout (floats)
  float* ws        = (float*)d_ws;
  float* T         = ws;                          // 1792*256 (legacy slot)
  float* anchor    = T + TROWS * 256;             // 16
  float* xyz_all   = anchor + 16;                 // B*NALL*3    = 64512
  float* feat_in   = xyz_all + B_ * NALL * 3;     // B*NALL*C    = 2752512
  float* feat_out  = feat_in + B_ * NALL * C;     // B*NALL*C    = 2752512
  float* AB        = feat_out + B_ * NALL * C;    // B*NALL*256  = 5505024
  float* Wcat      = AB + B_ * NALL * 256;        // 131*256     = 33536
  float* cb        = Wcat + 131 * 256;            // 256
  int*   idxA      = (int*)(cb + 256);            // B*NALL*8    = 172032 (stages 1/2)
  int*   idx3      = idxA + B_ * NALL * KNN;      // B*NALL*8    = 172032
  unsigned short* we2hi = (unsigned short*)(idx3 + B_ * NALL * KNN); // 16384
  unsigned short* we2lo = we2hi + C * C;                             // 16384
  int*   radmax    = (int*)(we2lo + C * C);       // B*NG3       = 1792 ints
  unsigned short* wcatT_hi = (unsigned short*)(radmax + B_ * NG3);   // 32768
  unsigned short* wcatT_lo = wcatT_hi + 256 * 128;                   // 32768
  unsigned short* w1T_hi   = wcatT_lo + 256 * 128;                   // 3*16384
  unsigned short* w1T_lo   = w1T_hi + 3 * C * C;                     // 3*16384
  // wbT aliases AB: fully consumed by t12_mfma before the first AB write.
  unsigned short* wbT_hi = (unsigned short*)AB;   // 256*1024 ushorts
  unsigned short* wbT_lo = wbT_hi + 256 * TOK;    // 256*1024 ushorts
  // Tpart aliases feat_out: last read at ab12_knn12; feat_out first written at
  // the stage-1/2 conv (after). KSPLIT*TROWS*256 = 1835008 <= 2752512 floats.
  float* Tpart = feat_out;

  // prep (fused)
  prep1_kernel<<<388, 256, 0, stream>>>(We1, We2, ctx_xyz, Wc1, Wq1, Wf1,
                                        Wcat, we2hi, we2lo, anchor, w1T_hi, w1T_lo);
  prep2_kernel<<<TOK / 4 + 1 + 128, 256, 0, stream>>>(Wp, bp, Wcat, be1,
                                                      wbT_hi, wbT_lo, cb,
                                                      wcatT_hi, wcatT_lo);
  build_all_kernel<<<72 + 12, 256, 0, stream>>>(ctx_xyz, noise_ctx, noise_prd, anchor,
                                                xyz_all, radmax);

  // token GEMM (split-K x4): Tpart[s] = [ctx_tok; pred_tok] @ Wbig[kslice s]
  t12_mfma_kernel<<<dim3(TROWS / 64, 2, KSPLIT), 256, 0, stream>>>(ctx_tok, pred_tok,
                                                                   wbT_hi, wbT_lo, Tpart);

  // ---- fused stage 1+2: AB assembly (all points) + knn1 + knn2 ----
  ab12_knn12_kernel<<<ABALL_BLOCKS + KNN1_BLOCKS + KNS_BLOCKS, 256, 0, stream>>>(
      Tpart, xyz_all, Wcat, cb, ctx_xyz, AB, idxA);
  conv_mfma_kernel<<<ABALL_BLOCKS, 256, 0, stream>>>(AB, idxA, we2hi, we2lo, be2, feat_in);
  offset_mfma_kernel<<<(B_ * NALL) / 64, 256, 0, stream>>>(
      feat_in,
      w1T_hi, w1T_lo, bc1, Wc2, bc2,                       // ctx set
      w1T_hi + C * C, w1T_lo + C * C, bq1, Wq2, bq2,       // pred set
      xyz_all, xyz_all, radmax);

  // ---- stage 3: global refinement ----
  pre3_knn3_kernel<<<P3G_BLOCKS + KNN3C_BLOCKS + KNN3P_BLOCKS, 256, 0, stream>>>(
      feat_in, xyz_all, Wcat, be1, wcatT_hi, wcatT_lo, ctx_xyz, anchor, radmax, AB, idx3);
  conv_mfma_kernel<<<ABALL_BLOCKS, 256, 0, stream>>>(AB, idx3, we2hi, we2lo, be2, feat_out);
  offset_mfma_kernel<<<(B_ * NALL) / 64, 256, 0, stream>>>(
      feat_out,
      w1T_hi + 2 * C * C, w1T_lo + 2 * C * C, bf1, Wf2, bf2,   // same set for all rows
      w1T_hi + 2 * C * C, w1T_lo + 2 * C * C, bf1, Wf2, bf2,
      xyz_all, out, nullptr);
}